// Round 4
// baseline (296.698 us; speedup 1.0000x reference)
//
#include <hip/hip_runtime.h>
#include <hip/hip_bf16.h>

// Inputs/outputs are FLOAT32 (reference dtype). bf16 used only internally for MFMA.
typedef __bf16 bf16_t;
typedef bf16_t bf16x8 __attribute__((ext_vector_type(8)));
typedef bf16_t bf16x4 __attribute__((ext_vector_type(4)));
typedef float  f32x4  __attribute__((ext_vector_type(4)));

#define MFMA(a,b,c) __builtin_amdgcn_mfma_f32_16x16x32_bf16((a),(b),(c),0,0,0)

// ---------------- small graph chain ----------------

// M = final_w[:, :256] @ gw_w  (stored bf16). Block 0 also zeroes accumulators.
__global__ __launch_bounds__(256) void k_M(const float* final_w, const float* gw_w,
                                           bf16_t* M16, float* xsum, float* fmaxb,
                                           float* cmaxb) {
  int o = blockIdx.x, c = threadIdx.x;
  __shared__ float fw[256];
  fw[c] = final_w[o*512 + c];
  __syncthreads();
  float acc = 0.f;
  for (int k = 0; k < 256; ++k) acc += fw[k] * gw_w[k*256 + c];
  M16[o*256 + c] = (bf16_t)acc;
  if (o == 0) {
    for (int i = c; i < 4096; i += 256) xsum[i] = 0.f;
    fmaxb[c] = 0.f;
    if (c < 16) cmaxb[c] = 0.f;
  }
}

// q,k,v = emb @ {wq,wk,wv} + bias   grid 3*20, block 320
__global__ __launch_bounds__(320) void k_qkv(const float* emb,
    const float* wq, const float* bq, const float* wk, const float* bk,
    const float* wv, const float* bv, float* qkv) {
  int mat = blockIdx.x / 20, row = blockIdx.x % 20, t = threadIdx.x;
  const float* W = mat == 0 ? wq : (mat == 1 ? wk : wv);
  const float* Bv = mat == 0 ? bq : (mat == 1 ? bk : bv);
  __shared__ float er[300];
  if (t < 300) er[t] = emb[row*300 + t];
  __syncthreads();
  if (t < 300) {
    float acc = Bv[t];
    for (int d = 0; d < 300; ++d) acc += er[d] * W[d*300 + t];
    qkv[(mat*20 + row)*300 + t] = acc;
  }
}

// attention on emb graph -> ev ; also adj_n.  1 block, 512 threads
__global__ __launch_bounds__(512) void k_attn(const float* emb, const float* wo, const float* bo,
                                              const float* adj, const float* qkv,
                                              float* ev, float* adjn) {
  __shared__ float qs[6000], ks[6000];
  __shared__ float att[400], wsum[20], n1[300], n2[300], drt[20];
  int t = threadIdx.x;
  for (int i = t; i < 6000; i += 512) { qs[i] = qkv[i]; ks[i] = qkv[6000 + i]; }
  if (t >= 480 && t < 500) {
    int i = t - 480; float s = 1.f;
    for (int j = 0; j < 20; ++j) s += adj[i*20 + j];
    drt[i] = rsqrtf(s);
  }
  __syncthreads();
  if (t < 400) {
    int i = t / 20, j = t % 20;
    float acc = 0.f;
    for (int d = 0; d < 300; ++d) acc += qs[i*300 + d] * ks[j*300 + d];
    att[t] = acc * 0.05773502691896258f;  // 1/sqrt(300)
  }
  __syncthreads();
  if (t < 20) {
    float m = -1e30f;
    for (int j = 0; j < 20; ++j) m = fmaxf(m, att[t*20 + j]);
    float s = 0.f;
    for (int j = 0; j < 20; ++j) { float e = __expf(att[t*20 + j] - m); att[t*20 + j] = e; s += e; }
    float inv = 1.f / s;
    for (int j = 0; j < 20; ++j) att[t*20 + j] *= inv;
  }
  __syncthreads();
  if (t < 20) {  // wsum[j] = mean over i of att[i][j]
    float s = 0.f;
    for (int i = 0; i < 20; ++i) s += att[i*20 + t];
    wsum[t] = s * 0.05f;
  }
  __syncthreads();
  if (t < 300) {
    const float* v = qkv + 12000;
    float acc = 0.f;
    for (int j = 0; j < 20; ++j) acc += wsum[j] * v[j*300 + t];
    n1[t] = acc;
  }
  __syncthreads();
  if (t < 300) {
    float acc = bo[t];
    for (int d = 0; d < 300; ++d) acc += n1[d] * wo[d*300 + t];
    n2[t] = acc;
  }
  __syncthreads();
  for (int i = t; i < 6000; i += 512) ev[i] = emb[i] + n2[i % 300];
  if (t < 400) {
    int i = t / 20, j = t % 20;
    float a = adj[t] + (i == j ? 1.f : 0.f);
    adjn[t] = drt[i] * a * drt[j];
  }
}

// h1 = ev @ gc1_w   grid 20, block 256
__global__ __launch_bounds__(256) void k_h1(const float* ev, const float* gc1_w, float* h1) {
  int n = blockIdx.x, c = threadIdx.x;
  __shared__ float er[300];
  for (int i = c; i < 300; i += 256) er[i] = ev[n*300 + i];
  __syncthreads();
  float acc = 0.f;
  for (int d = 0; d < 300; ++d) acc += er[d] * gc1_w[d*256 + c];
  h1[n*256 + c] = acc;
}

// g1 = relu(adjn @ h1) ; h2 = g1 @ gc2_w   grid 20, block 256
__global__ __launch_bounds__(256) void k_g1h2(const float* adjn, const float* h1,
                                              const float* gc2_w, float* h2) {
  int n = blockIdx.x, c = threadIdx.x;
  __shared__ float ar[20], g1r[256];
  if (c < 20) ar[c] = adjn[n*20 + c];
  __syncthreads();
  float acc = 0.f;
  for (int m = 0; m < 20; ++m) acc += ar[m] * h1[m*256 + c];
  g1r[c] = fmaxf(acc, 0.f);
  __syncthreads();
  float h = 0.f;
  for (int d = 0; d < 256; ++d) h += g1r[d] * gc2_w[d*256 + c];
  h2[n*256 + c] = h;
}

// g2 = relu(adjn @ h2); rg = sum_n g2; u = fw2 @ rg.  1 block 256
__global__ __launch_bounds__(256) void k_g2u(const float* adjn, const float* h2,
                                             const float* final_w, float* u) {
  int c = threadIdx.x;
  __shared__ float an[400], rg[256];
  for (int i = c; i < 400; i += 256) an[i] = adjn[i];
  __syncthreads();
  float gs = 0.f;
  for (int n = 0; n < 20; ++n) {
    float acc = 0.f;
    for (int m = 0; m < 20; ++m) acc += an[n*20 + m] * h2[m*256 + c];
    gs += fmaxf(acc, 0.f);
  }
  rg[c] = gs;
  __syncthreads();
  float acc = 0.f;
  for (int k = 0; k < 256; ++k) acc += final_w[c*512 + 256 + k] * rg[k];
  u[c] = acc;
}

// ---------------- big path ----------------

// phi -> fB=relu(phi+b) bf16, fmax per (b,m), csum[b,q]=col sums + cmax, s_raw, xsum.
// grid (9, 16): role 0..7 -> phi/s/csum for 128 hw; role 8 -> xsum.
__global__ __launch_bounds__(256) void k_phis(const float* x, const float* phi_w,
    const float* phi_b, const float* s2l_w,
    bf16_t* fB, float* fmaxb, float* s_raw, float* xsum, float* csum, float* cmaxb) {
  int b = blockIdx.y, role = blockIdx.x, t = threadIdx.x;
  const float* xb = x + b*262144;
  if (role == 8) {
    int wv = t >> 6, lane = t & 63;
    for (int c = wv; c < 256; c += 4) {
      float acc = 0.f;
      const float* p = xb + c*1024 + lane;
      #pragma unroll
      for (int k = 0; k < 16; ++k) acc += p[k*64];
      #pragma unroll
      for (int off = 32; off; off >>= 1) acc += __shfl_down(acc, off, 64);
      if (lane == 0) atomicAdd(&xsum[b*256 + c], acc);
    }
    return;
  }
  __shared__ float pw[4096], wi[256], pb[16];
  __shared__ float phs[128][18];
  __shared__ unsigned fmu[16];
  __shared__ unsigned cmu;
  for (int i = t; i < 4096; i += 256) pw[i] = phi_w[i];
  wi[t] = s2l_w[t];
  if (t < 16) { pb[t] = phi_b[t]; fmu[t] = 0u; }
  if (t == 0) cmu = 0u;
  __syncthreads();
  int hwl = t & 127, half = t >> 7;
  int hw = role*128 + hwl;
  float ph[16];
  #pragma unroll
  for (int o = 0; o < 16; ++o) ph[o] = 0.f;
  float sacc = 0.f;
  for (int ci = 0; ci < 128; ++ci) {
    int c = half*128 + ci;
    float xv = xb[c*1024 + hw];
    sacc += wi[c] * xv;
    #pragma unroll
    for (int o = 0; o < 16; ++o) ph[o] += pw[o*256 + c] * xv;
  }
  if (half == 0) {
    #pragma unroll
    for (int o = 0; o < 16; ++o) phs[hwl][o] = ph[o];
    phs[hwl][16] = sacc;
  }
  __syncthreads();
  if (half == 1) {
    #pragma unroll
    for (int o = 0; o < 16; ++o) phs[hwl][o] += ph[o];
    s_raw[b*1024 + hw] = phs[hwl][16] + sacc;
  }
  __syncthreads();
  float csacc = 0.f;
  #pragma unroll
  for (int i = 0; i < 8; ++i) {
    int j = i*256 + t;
    int o = j >> 7, hl = j & 127;     // hl == t&127; o covers 8 values per thread
    float val = fmaxf(phs[hl][o] + pb[o], 0.f);
    bf16_t bv = (bf16_t)val;
    atomicMax(&fmu[o], __float_as_uint((float)bv));
    fB[b*16384 + o*1024 + role*128 + hl] = bv;
    csacc += (float)bv;
  }
  if (half == 0) phs[hwl][17] = csacc;
  __syncthreads();                       // fmu complete; csacc halves staged
  if (half == 1) {
    float cs = phs[hwl][17] + csacc;     // full c[q] = sum_m fB[b,m,q]
    csum[b*1024 + hw] = cs;
    atomicMax(&cmu, __float_as_uint(cs));  // cs >= 0
  }
  if (t < 16) atomicMax((unsigned*)&fmaxb[b*16 + t], fmu[t]);
  __syncthreads();
  if (t == 0) atomicMax((unsigned*)&cmaxb[b], cmu);
}

// dgd = sigmoid(g) - 0.5 = 0.5*tanh(g/2); mcol = softmax_p(s_raw).  grid 16
__global__ __launch_bounds__(256) void k_dgm(const float* xsum, const float* glob_w,
    const float* s_raw, float* dgd, float* mcol) {
  int b = blockIdx.x, t = threadIdx.x;
  __shared__ float xm[256], red[8];
  xm[t] = xsum[b*256 + t] * (1.f / 1024.f);
  __syncthreads();
  if (t < 16) {
    float g = 0.f;
    for (int c = 0; c < 256; ++c) g += glob_w[t*256 + c] * xm[c];
    dgd[b*16 + t] = 0.5f * tanhf(0.5f * g);   // sigmoid(g) - 0.5
  }
  // mcol softmax over 1024
  float v[4]; float m = -1e30f;
  #pragma unroll
  for (int i = 0; i < 4; ++i) { v[i] = s_raw[b*1024 + t + i*256]; m = fmaxf(m, v[i]); }
  #pragma unroll
  for (int off = 32; off; off >>= 1) m = fmaxf(m, __shfl_xor(m, off, 64));
  if ((t & 63) == 0) red[t >> 6] = m;
  __syncthreads();
  float bm = fmaxf(fmaxf(red[0], red[1]), fmaxf(red[2], red[3]));
  float e[4]; float sum = 0.f;
  #pragma unroll
  for (int i = 0; i < 4; ++i) { e[i] = __expf(v[i] - bm); sum += e[i]; }
  #pragma unroll
  for (int off = 32; off; off >>= 1) sum += __shfl_xor(sum, off, 64);
  if ((t & 63) == 0) red[4 + (t >> 6)] = sum;
  __syncthreads();
  float inv = 1.f / (red[4] + red[5] + red[6] + red[7]);
  #pragma unroll
  for (int i = 0; i < 4; ++i) mcol[b*1024 + t + i*256] = e[i] * inv;
}

// Fused main. S[p,q] = sum_m e'[p,m] f[m,q]  (MFMA, K 16->32 pad)  + 0.5*a[p]*c[q] (fp32).
// Single pass over q: E=exp(S-Mb), rowsum rs and S2u[p,c] += E @ x_r; then
// T = x_r - S2u/rs in LDS; GEMM2 out = relu(M @ T^T + mcol*u + x).
// grid (16 p-tiles, 16 b), block 256.
__global__ __launch_bounds__(256) void k_main(const float* x, const bf16_t* fB,
    const bf16_t* M16, const float* fmaxb, const float* mcol, const float* u,
    const float* dgd, const float* csum, const float* cmaxb, float* out) {
  int b = blockIdx.y, p0 = blockIdx.x * 64;
  int t = threadIdx.x, w = t >> 6, l = t & 63, lr = l & 15, quad = l >> 4;
  __shared__ __align__(16) char smem[33792];          // union: phase1 | T_ls
  bf16_t* e_s = (bf16_t*)smem;                        // [64][40] e' (m>=16 zero)
  bf16_t* fT  = (bf16_t*)(smem + 5120);               // [32][40] f tile (m>=16 zero)
  bf16_t* PT  = (bf16_t*)(smem + 7680);               // [64][40] E tiles [p][q]
  bf16_t* T_ls = (bf16_t*)smem;                       // [64][264] phase 2
  __shared__ float Mb_s[64], fmax_s[16], u_s[256], rsinv_s[64], dgd_s[16];
  __shared__ float c_s[1024], ha_s[64];               // c[q]; 0.5*a[p]
  const float*  xb  = x  + b*262144;
  const bf16_t* fBb = fB + b*16384;
  for (int i = t; i < 2560; i += 256) e_s[i] = (bf16_t)0.f;
  for (int i = t; i < 1280; i += 256) fT[i] = (bf16_t)0.f;
  u_s[t] = u[t];
  for (int i = t; i < 1024; i += 256) c_s[i] = csum[b*1024 + i];
  if (t < 16) { fmax_s[t] = fmaxb[b*16 + t]; dgd_s[t] = dgd[b*16 + t]; }
  __syncthreads();
  for (int i = t; i < 1024; i += 256) {      // e'[p,m] = x_phi * (sig(g[m])-0.5)
    int p = i >> 4, m = i & 15;
    e_s[p*40 + m] = (bf16_t)((float)fBb[p0*16 + i] * dgd_s[m]);
  }
  __syncthreads();
  if (t < 64) {
    float a = 0.f;
    #pragma unroll
    for (int m = 0; m < 16; ++m) a += (float)fBb[(p0 + t)*16 + m];
    float ha = 0.5f * a;
    ha_s[t] = ha;
    float mb = ha * cmaxb[b];
    #pragma unroll
    for (int m = 0; m < 16; ++m) mb += fmaxf((float)e_s[t*40 + m], 0.f) * fmax_s[m];
    Mb_s[t] = mb;  // exact upper bound on row max of S
  }
  __syncthreads();
  bf16x8 be = *(const bf16x8*)(e_s + (w*16 + lr)*40 + quad*8);  // wave w: p-sub w
  float mb_lane = Mb_s[w*16 + lr];
  float ha_lane = ha_s[w*16 + lr];
  float rs = 0.f;
  f32x4 acc[4][4];  // S2u[p = pf*16+quad*4+r][c = w*64+cf*16+lr]
  #pragma unroll
  for (int i = 0; i < 4; ++i)
    #pragma unroll
    for (int j = 0; j < 4; ++j) acc[i][j] = (f32x4){0.f, 0.f, 0.f, 0.f};
  for (int st = 0; st < 32; ++st) {
    int e0 = t, e1 = t + 256;  // 512 elems: m = e>>5, qi = e&31
    fT[(e0 & 31)*40 + (e0 >> 5)] = fBb[(e0 >> 5)*1024 + st*32 + (e0 & 31)];
    fT[(e1 & 31)*40 + (e1 >> 5)] = fBb[(e1 >> 5)*1024 + st*32 + (e1 & 31)];
    __syncthreads();
    bf16x8 a0 = *(const bf16x8*)(fT + lr*40 + quad*8);
    bf16x8 a1 = *(const bf16x8*)(fT + (16 + lr)*40 + quad*8);
    f32x4 z = {0.f, 0.f, 0.f, 0.f};
    f32x4 s0 = MFMA(a0, be, z);   // D[q=quad*4+r][p=w*16+lr]
    f32x4 s1 = MFMA(a1, be, z);
    bf16x4 p0v, p1v;
    #pragma unroll
    for (int r = 0; r < 4; ++r) {
      float S0 = s0[r] + ha_lane * c_s[st*32 + quad*4 + r];
      float S1 = s1[r] + ha_lane * c_s[st*32 + 16 + quad*4 + r];
      float E0 = __expf(S0 - mb_lane);
      float E1 = __expf(S1 - mb_lane);
      rs += E0 + E1;
      p0v[r] = (bf16_t)E0; p1v[r] = (bf16_t)E1;
    }
    *(bf16x4*)(PT + (w*16 + lr)*40 + quad*4)      = p0v;  // q-local 0..15
    *(bf16x4*)(PT + (w*16 + lr)*40 + 16 + quad*4) = p1v;  // q-local 16..31
    __syncthreads();
    bf16x8 ap[4];
    #pragma unroll
    for (int pf = 0; pf < 4; ++pf)
      ap[pf] = *(const bf16x8*)(PT + (pf*16 + lr)*40 + quad*8);
    #pragma unroll
    for (int cf = 0; cf < 4; ++cf) {
      bf16x8 bv;
      const float* xp = xb + (st*32 + quad*8)*256 + w*64 + cf*16 + lr;
      #pragma unroll
      for (int j = 0; j < 8; ++j) bv[j] = (bf16_t)xp[j*256];   // x_r[q][c] raw reshape
      #pragma unroll
      for (int pf = 0; pf < 4; ++pf) acc[pf][cf] = MFMA(ap[pf], bv, acc[pf][cf]);
    }
  }
  rs += __shfl_xor(rs, 16, 64);
  rs += __shfl_xor(rs, 32, 64);          // full rowsum for p = w*16+lr
  float inv_l = 1.f / fmaxf(rs, 1e-30f);
  if (l < 16) rsinv_s[w*16 + lr] = inv_l;
  __syncthreads();   // rsinv visible; all PT/fT/e_s reads drained -> T_ls may overwrite
  #pragma unroll
  for (int pf = 0; pf < 4; ++pf)
    #pragma unroll
    for (int cf = 0; cf < 4; ++cf)
      #pragma unroll
      for (int r = 0; r < 4; ++r) {
        int p = pf*16 + quad*4 + r;
        int c = w*64 + cf*16 + lr;
        float tv = xb[(p0 + p)*256 + c] - acc[pf][cf][r] * rsinv_s[p];
        T_ls[p*264 + c] = (bf16_t)tv;    // spiral[p][c]
      }
  __syncthreads();
  f32x4 acc2[4][4];  // D2[o = w*64+of*16+quad*4+r][p = pf*16+lr]
  #pragma unroll
  for (int i = 0; i < 4; ++i)
    #pragma unroll
    for (int j = 0; j < 4; ++j) acc2[i][j] = (f32x4){0.f, 0.f, 0.f, 0.f};
  for (int c0 = 0; c0 < 256; c0 += 32) {
    bf16x8 am[4], bt[4];
    #pragma unroll
    for (int of = 0; of < 4; ++of)
      am[of] = *(const bf16x8*)(M16 + (w*64 + of*16 + lr)*256 + c0 + quad*8);
    #pragma unroll
    for (int pf = 0; pf < 4; ++pf)
      bt[pf] = *(const bf16x8*)(T_ls + (pf*16 + lr)*264 + c0 + quad*8);
    #pragma unroll
    for (int of = 0; of < 4; ++of)
      #pragma unroll
      for (int pf = 0; pf < 4; ++pf) acc2[of][pf] = MFMA(am[of], bt[pf], acc2[of][pf]);
  }
  float* outb = out + b*262144;
  #pragma unroll
  for (int of = 0; of < 4; ++of)
    #pragma unroll
    for (int pf = 0; pf < 4; ++pf)
      #pragma unroll
      for (int r = 0; r < 4; ++r) {
        int o = w*64 + of*16 + quad*4 + r;
        int pg = p0 + pf*16 + lr;
        float v = acc2[of][pf][r] + mcol[b*1024 + pg] * u_s[o] + xb[o*1024 + pg];
        outb[o*1024 + pg] = fmaxf(v, 0.f);
      }
}

// ---------------- launch ----------------

extern "C" void kernel_launch(void* const* d_in, const int* in_sizes, int n_in,
                              void* d_out, int out_size, void* d_ws, size_t ws_size,
                              hipStream_t stream) {
  (void)in_sizes; (void)n_in; (void)out_size; (void)ws_size;
  const float* x       = (const float*)d_in[0];
  const float* emb     = (const float*)d_in[1];
  const float* adj     = (const float*)d_in[2];
  const float* wq      = (const float*)d_in[3];
  const float* bq      = (const float*)d_in[4];
  const float* wk      = (const float*)d_in[5];
  const float* bk      = (const float*)d_in[6];
  const float* wv      = (const float*)d_in[7];
  const float* bv      = (const float*)d_in[8];
  const float* wo      = (const float*)d_in[9];
  const float* bo      = (const float*)d_in[10];
  const float* phi_w   = (const float*)d_in[11];
  const float* phi_b   = (const float*)d_in[12];
  const float* glob_w  = (const float*)d_in[13];
  const float* gc1_w   = (const float*)d_in[14];
  const float* gc2_w   = (const float*)d_in[15];
  const float* gw_w    = (const float*)d_in[16];
  const float* s2l_w   = (const float*)d_in[17];
  const float* final_w = (const float*)d_in[19];
  float* out = (float*)d_out;

  float* W = (float*)d_ws;
  float* qkv   = W + 0;        // 18000
  float* ev    = W + 18048;    // 6000
  float* adjn  = W + 24064;    // 400
  float* h1    = W + 24512;    // 5120
  float* h2    = W + 29632;    // 5120
  float* u     = W + 34752;    // 256
  float* xsum  = W + 35008;    // 4096
  float* s_raw = W + 39360;    // 16384
  float* mcol  = W + 55744;    // 16384
  float* fmaxb = W + 72128;    // 256
  float* dgd   = W + 72384;    // 256
  float* csum  = W + 72640;    // 16384
  float* cmaxb = W + 89024;    // 16
  bf16_t* M16 = (bf16_t*)((char*)d_ws + 356352);           // 65536 bf16 (128 KB)
  bf16_t* fB  = (bf16_t*)((char*)d_ws + 356352 + 131072);  // 262144 bf16 (512 KB)
  // total ws usage ~0.97 MB

  k_M    <<<256, 256, 0, stream>>>(final_w, gw_w, M16, xsum, fmaxb, cmaxb);
  k_qkv  <<<60, 320, 0, stream>>>(emb, wq, bq, wk, bk, wv, bv, qkv);
  k_attn <<<1, 512, 0, stream>>>(emb, wo, bo, adj, qkv, ev, adjn);
  k_h1   <<<20, 256, 0, stream>>>(ev, gc1_w, h1);
  k_g1h2 <<<20, 256, 0, stream>>>(adjn, h1, gc2_w, h2);
  k_g2u  <<<1, 256, 0, stream>>>(adjn, h2, final_w, u);
  k_phis <<<dim3(9, 16), 256, 0, stream>>>(x, phi_w, phi_b, s2l_w, fB, fmaxb, s_raw, xsum, csum, cmaxb);
  k_dgm  <<<16, 256, 0, stream>>>(xsum, glob_w, s_raw, dgd, mcol);
  k_main <<<dim3(16, 16), 256, 0, stream>>>(x, fB, M16, fmaxb, mcol, u, dgd, csum, cmaxb, out);
}